// Round 3
// baseline (468.034 us; speedup 1.0000x reference)
//
#include <hip/hip_runtime.h>
#include <cfloat>
#include <cmath>

#define NHEADS 3
#define HIDC   64
#define HCC    192   // NHEADS*HIDC
#define EMBC   128

typedef unsigned short bhalf;

// ---- monotone float<->uint mapping for atomicMax on floats (init = 0) ----
__device__ __forceinline__ unsigned fmap(float f) {
  unsigned u = __float_as_uint(f);
  return (u & 0x80000000u) ? ~u : (u | 0x80000000u);
}
__device__ __forceinline__ float funmap(unsigned m) {
  return __uint_as_float((m & 0x80000000u) ? (m ^ 0x80000000u) : ~m);
}

__device__ __forceinline__ unsigned f2bf(float f) {   // RNE fp32 -> bf16 bits
  unsigned u = __float_as_uint(f);
  return (u + 0x7FFFu + ((u >> 16) & 1u)) >> 16;
}

__device__ __forceinline__ void fma4(float4& acc, float s, const float4& w) {
  acc.x = fmaf(s, w.x, acc.x);
  acc.y = fmaf(s, w.y, acc.y);
  acc.z = fmaf(s, w.z, acc.z);
  acc.w = fmaf(s, w.w, acc.w);
}

// ---- fused xl|xr = pe @ [Wl;Wr]^T + bias  -> bf16; pj = xl_f32 . Wout fused ----
// Tile: 64 nodes x 384 cols. Thread (ig,jg) = (t>>4, t&15) computes
// nodes ig*4..+3, cols {c6*64 + jg*4 ..+3 : c6 in 0..5}. acc = float4[4][6].
__global__ __launch_bounds__(256) void gemm_kernel(
    const float* __restrict__ pe,
    const float* __restrict__ Wl, const float* __restrict__ bl,
    const float* __restrict__ Wr, const float* __restrict__ br,
    const float* __restrict__ Wout,
    bhalf* __restrict__ xlb, bhalf* __restrict__ xrb,
    float* __restrict__ pj, int N)
{
  __shared__ float As[64][132];   // node-major, pad 4
  __shared__ float Ws[16][388];   // k-major tile, col reads contiguous per wave
  const int t  = threadIdx.x;
  const int n0 = blockIdx.x * 64;
  const int ig = t >> 4;
  const int jg = t & 15;

  // stage pe tile (once)
  for (int f = t; f < 64 * 32; f += 256) {
    int row = f >> 5;
    int c4  = (f & 31) << 2;
    int n = n0 + row;
    float4 v = make_float4(0.f, 0.f, 0.f, 0.f);
    if (n < N) v = *(const float4*)(pe + (size_t)n * EMBC + c4);
    As[row][c4]   = v.x; As[row][c4+1] = v.y;
    As[row][c4+2] = v.z; As[row][c4+3] = v.w;
  }

  float4 acc[4][6];
  #pragma unroll
  for (int a = 0; a < 4; ++a)
    #pragma unroll
    for (int c = 0; c < 6; ++c) acc[a][c] = make_float4(0.f, 0.f, 0.f, 0.f);

  for (int kt = 0; kt < EMBC; kt += 16) {
    __syncthreads();   // protects As on first iter, Ws reuse on later iters
    for (int f = t; f < 1536; f += 256) {   // Ws[kk][c] = W[c][kt+kk]
      int c  = f >> 2;
      int kq = f & 3;
      const float* wp = (c < HCC ? Wl + (size_t)c * EMBC
                                 : Wr + (size_t)(c - HCC) * EMBC) + kt + kq * 4;
      float4 v = *(const float4*)wp;
      Ws[kq*4+0][c] = v.x; Ws[kq*4+1][c] = v.y;
      Ws[kq*4+2][c] = v.z; Ws[kq*4+3][c] = v.w;
    }
    __syncthreads();

    #pragma unroll
    for (int k4 = 0; k4 < 16; k4 += 4) {
      float4 av[4];
      #pragma unroll
      for (int a = 0; a < 4; ++a)
        av[a] = *(const float4*)&As[ig*4 + a][kt + k4];
      #pragma unroll
      for (int kk = 0; kk < 4; ++kk) {
        #pragma unroll
        for (int c6 = 0; c6 < 6; ++c6) {
          float4 w = *(const float4*)&Ws[k4 + kk][c6*64 + jg*4];
          #pragma unroll
          for (int a = 0; a < 4; ++a)
            fma4(acc[a][c6], ((const float*)&av[a])[kk], w);
        }
      }
    }
  }

  // epilogue: + bias, bf16-pack to xlb/xrb, fp32 pj partials for xl heads
  const float4 wout4 = *(const float4*)(Wout + jg*4);
  float pjp[4][3];
  #pragma unroll
  for (int c6 = 0; c6 < 6; ++c6) {
    int col = c6*64 + jg*4;
    const float* bp = (col < HCC) ? (bl + col) : (br + col - HCC);
    float4 b = *(const float4*)bp;
    bhalf* xo = (col < HCC) ? xlb : xrb;
    int colo = (col < HCC) ? col : col - HCC;
    #pragma unroll
    for (int a = 0; a < 4; ++a) {
      int n = n0 + ig*4 + a;
      float4 r = acc[a][c6];
      r.x += b.x; r.y += b.y; r.z += b.z; r.w += b.w;
      if (c6 < 3)
        pjp[a][c6] = r.x*wout4.x + r.y*wout4.y + r.z*wout4.z + r.w*wout4.w;
      if (n < N) {
        uint2 p;
        p.x = f2bf(r.x) | (f2bf(r.y) << 16);
        p.y = f2bf(r.z) | (f2bf(r.w) << 16);
        *(uint2*)(xo + (size_t)n * HCC + colo) = p;
      }
    }
  }
  // reduce pj partials across the 16 jg-lanes (same ig = contiguous 16 lanes)
  #pragma unroll
  for (int a = 0; a < 4; ++a)
    #pragma unroll
    for (int h = 0; h < 3; ++h) {
      float v = pjp[a][h];
      v += __shfl_xor(v, 1);
      v += __shfl_xor(v, 2);
      v += __shfl_xor(v, 4);
      v += __shfl_xor(v, 8);
      int n = n0 + ig*4 + a;
      if (jg == 0 && n < N) pj[n*3 + h] = v;
    }
}

// ---- single edge pass: 48 active lanes, 4 bf16 (8B) per lane per matrix ----
__global__ __launch_bounds__(256) void edge_kernel(
    const int* __restrict__ ei, const float* __restrict__ ea,
    const bhalf* __restrict__ xlb, const bhalf* __restrict__ xrb,
    const float* __restrict__ pj, const float* __restrict__ We,
    const float* __restrict__ att,
    float* __restrict__ asum, float* __restrict__ numer, int E)
{
  int e    = (blockIdx.x * 256 + threadIdx.x) >> 6;   // one wave per edge
  int lane = threadIdx.x & 63;
  if (e >= E) return;
  int src = ei[e];
  int dst = ei[E + e];
  float eav = ea[e];

  float s = 0.f;
  if (lane < 48) {
    uint2 ul = *(const uint2*)(xlb + (size_t)src * HCC + lane*4);
    uint2 ur = *(const uint2*)(xrb + (size_t)dst * HCC + lane*4);
    const float4 wev = *(const float4*)(We + lane*4);
    const float4 atv = *(const float4*)(att + lane*4);
    float m0 = __uint_as_float(ul.x << 16)          + __uint_as_float(ur.x << 16)          + eav * wev.x;
    float m1 = __uint_as_float(ul.x & 0xFFFF0000u)  + __uint_as_float(ur.x & 0xFFFF0000u)  + eav * wev.y;
    float m2 = __uint_as_float(ul.y << 16)          + __uint_as_float(ur.y << 16)          + eav * wev.z;
    float m3 = __uint_as_float(ul.y & 0xFFFF0000u)  + __uint_as_float(ur.y & 0xFFFF0000u)  + eav * wev.w;
    s = (m0 > 0.f ? m0 : 0.2f*m0) * atv.x
      + (m1 > 0.f ? m1 : 0.2f*m1) * atv.y
      + (m2 > 0.f ? m2 : 0.2f*m2) * atv.z
      + (m3 > 0.f ? m3 : 0.2f*m3) * atv.w;
  }
  // reduce within 16-lane groups (one head per group)
  s += __shfl_xor(s, 8);
  s += __shfl_xor(s, 4);
  s += __shfl_xor(s, 2);
  s += __shfl_xor(s, 1);
  if (lane < 48 && (lane & 15) == 0) {
    int h = lane >> 4;
    float ex = __expf(s);   // |a| small by construction: max-free softmax safe
    atomicAdd(asum  + dst*3 + h, ex);
    atomicAdd(numer + dst*3 + h, ex * pj[src*3 + h]);
  }
}

// ---- scores[n] = (1/3) sum_h numer/asum ; block-reduce max ----
__global__ __launch_bounds__(256) void score_kernel(
    const float* __restrict__ numer, const float* __restrict__ asum,
    float* __restrict__ scores, unsigned* __restrict__ smax, int N)
{
  int n = blockIdx.x * 256 + threadIdx.x;
  int t = threadIdx.x;
  float s = -FLT_MAX;
  if (n < N) {
    float acc = 0.f;
    #pragma unroll
    for (int h = 0; h < 3; ++h) {
      float d = asum[n*3 + h];
      if (d > 0.f) acc += numer[n*3 + h] / d;   // empty segment -> 0 (matches ref)
    }
    s = acc / 3.f;
    scores[n] = s;
  }
  __shared__ float red[256];
  red[t] = s;
  __syncthreads();
  for (int w = 128; w; w >>= 1) {
    if (t < w) red[t] = fmaxf(red[t], red[t + w]);
    __syncthreads();
  }
  if (t == 0) atomicMax(smax, fmap(red[0]));
}

__global__ __launch_bounds__(256) void expsum_kernel(
    const float* __restrict__ scores, const unsigned* __restrict__ smax,
    float* __restrict__ sumexp, float* __restrict__ out, int N)
{
  int n = blockIdx.x * 256 + threadIdx.x;
  int t = threadIdx.x;
  float m = funmap(*smax);
  float e = 0.f;
  if (n < N) {
    e = expf(scores[n] - m);
    out[n] = e;
  }
  __shared__ float red[256];
  red[t] = e;
  __syncthreads();
  for (int w = 128; w; w >>= 1) {
    if (t < w) red[t] += red[t + w];
    __syncthreads();
  }
  if (t == 0) atomicAdd(sumexp, red[0]);
}

__global__ __launch_bounds__(256) void norm_kernel(
    float* __restrict__ out, const float* __restrict__ sumexp, int N)
{
  int n = blockIdx.x * 256 + threadIdx.x;
  if (n < N) out[n] /= *sumexp;
}

extern "C" void kernel_launch(void* const* d_in, const int* in_sizes, int n_in,
                              void* d_out, int out_size, void* d_ws, size_t ws_size,
                              hipStream_t stream) {
  const int*   ei   = (const int*)  d_in[0];
  const float* ea   = (const float*)d_in[1];
  const float* pe   = (const float*)d_in[2];
  // d_in[3] sim_w: softmax over 1 element == 1.0 -> unused
  const float* Wl   = (const float*)d_in[4];
  const float* bl   = (const float*)d_in[5];
  const float* Wr   = (const float*)d_in[6];
  const float* br   = (const float*)d_in[7];
  const float* We   = (const float*)d_in[8];
  const float* att  = (const float*)d_in[9];
  // d_in[10] bias_gnn, d_in[12] bout: constant shift of scores -> softmax-invariant, unused
  const float* Wout = (const float*)d_in[11];

  const int E = in_sizes[0] / 2;
  const int N = in_sizes[2] / EMBC;
  float* out = (float*)d_out;

  // workspace layout
  float* ws      = (float*)d_ws;
  float* asum    = ws;                        // 3N floats
  float* numer   = ws + (size_t)3 * N;        // 3N floats
  unsigned* smax = (unsigned*)(ws + (size_t)6 * N);  // 1 (mapped, 0 == -inf)
  float* sumexp  = ws + (size_t)6 * N + 1;    // 1
  float* pj      = ws + (size_t)6 * N + 16;   // 3N floats
  float* scores  = pj + (size_t)3 * N;        // N floats
  bhalf* xlb     = (bhalf*)(scores + N);      // N*192 bf16
  bhalf* xrb     = xlb + (size_t)N * HCC;     // N*192 bf16

  // zero the accumulators (ws is poisoned 0xAA before every call)
  hipMemsetAsync(ws, 0, ((size_t)6 * N + 2) * sizeof(float), stream);

  gemm_kernel  <<<(N + 63) / 64,   256, 0, stream>>>(pe, Wl, bl, Wr, br, Wout, xlb, xrb, pj, N);
  edge_kernel  <<<(E + 3) / 4,     256, 0, stream>>>(ei, ea, xlb, xrb, pj, We, att, asum, numer, E);
  score_kernel <<<(N + 255) / 256, 256, 0, stream>>>(numer, asum, scores, smax, N);
  expsum_kernel<<<(N + 255) / 256, 256, 0, stream>>>(scores, smax, sumexp, out, N);
  norm_kernel  <<<(N + 255) / 256, 256, 0, stream>>>(out, sumexp, N);
}

// Round 4
// 293.848 us; speedup vs baseline: 1.5928x; 1.5928x over previous
//
#include <hip/hip_runtime.h>
#include <cfloat>
#include <cmath>

#define NHEADS 3
#define HIDC   64
#define HCC    192   // NHEADS*HIDC
#define EMBC   128
#define WCOLS  384   // 2*HCC (Wl rows ++ Wr rows)

typedef unsigned short bhalf;
typedef __attribute__((ext_vector_type(8))) short bf16x8;
typedef __attribute__((ext_vector_type(4))) float f32x4;

// ---- monotone float<->uint mapping for atomicMax on floats (init = 0) ----
__device__ __forceinline__ unsigned fmap(float f) {
  unsigned u = __float_as_uint(f);
  return (u & 0x80000000u) ? ~u : (u | 0x80000000u);
}
__device__ __forceinline__ float funmap(unsigned m) {
  return __uint_as_float((m & 0x80000000u) ? (m ^ 0x80000000u) : ~m);
}

__device__ __forceinline__ unsigned f2bf(float f) {   // RNE fp32 -> bf16 bits
  unsigned u = __float_as_uint(f);
  return (u + 0x7FFFu + ((u >> 16) & 1u)) >> 16;
}

// ---- prep: Wb (bf16 [384][128]), vh[h][k] = sum_c Wout[c]*Wl[h*64+c][k],
//            biasc[384] = bl++br, ch[h] = sum_c bl[h*64+c]*Wout[c] ----
__global__ __launch_bounds__(256) void prep_kernel(
    const float* __restrict__ Wl, const float* __restrict__ Wr,
    const float* __restrict__ bl, const float* __restrict__ br,
    const float* __restrict__ Wout,
    bhalf* __restrict__ Wb, float* __restrict__ vh,
    float* __restrict__ biasc, float* __restrict__ ch)
{
  int gt = blockIdx.x * 256 + threadIdx.x;
  if (gt < WCOLS * EMBC) {                       // Wb
    int c = gt >> 7, k = gt & 127;
    float v = (c < HCC) ? Wl[c * EMBC + k] : Wr[(c - HCC) * EMBC + k];
    Wb[gt] = (bhalf)f2bf(v);
  } else if (gt < WCOLS * EMBC + 384) {          // vh (3*128)
    int i = gt - WCOLS * EMBC;
    int h = i >> 7, k = i & 127;
    float s = 0.f;
    for (int c = 0; c < HIDC; ++c)
      s += Wout[c] * Wl[(h * HIDC + c) * EMBC + k];
    vh[i] = s;
  } else if (gt < WCOLS * EMBC + 768) {          // biasc
    int c = gt - WCOLS * EMBC - 384;
    biasc[c] = (c < HCC) ? bl[c] : br[c - HCC];
  } else if (gt < WCOLS * EMBC + 771) {          // ch
    int h = gt - WCOLS * EMBC - 768;
    float s = 0.f;
    for (int c = 0; c < HIDC; ++c) s += bl[h * HIDC + c] * Wout[c];
    ch[h] = s;
  }
}

// ---- MFMA GEMM: [xl|xr](bf16) = pe @ [Wl;Wr]^T + bias ----
// Block: 64 nodes x 384 cols, 4 waves. Wave w owns nodes n0+16w..+15.
// Frag layout (m91-verified B^T pattern): A[m=lane&15][k=(lane>>4)*8+j],
// B = W rows loaded identically; D: col=lane&15, row=(lane>>4)*4+reg.
__global__ __launch_bounds__(256) void gemm_kernel(
    const float* __restrict__ pe, const bhalf* __restrict__ Wb,
    const float* __restrict__ biasc,
    bhalf* __restrict__ xlb, bhalf* __restrict__ xrb, int N)
{
  __shared__ bhalf Ls[64][392];   // 64 x 384 tile (+8 pad), 16B-aligned rows
  const int tid  = threadIdx.x;
  const int w    = tid >> 6;
  const int lane = tid & 63;
  const int m    = lane & 15;
  const int q    = lane >> 4;
  const int n0   = blockIdx.x * 64;
  const int node = n0 + w * 16 + m;
  const size_t prow = (size_t)(node < N ? node : N - 1) * EMBC;

  // A fragments: pe fp32 -> bf16, 8 k-elems per lane per k-tile
  bf16x8 afrag[4];
  #pragma unroll
  for (int kt = 0; kt < 4; ++kt) {
    const float* p = pe + prow + kt * 32 + q * 8;
    float4 x = *(const float4*)p;
    float4 y = *(const float4*)(p + 4);
    union { bf16x8 v; unsigned short u[8]; } uu;
    uu.u[0] = f2bf(x.x); uu.u[1] = f2bf(x.y); uu.u[2] = f2bf(x.z); uu.u[3] = f2bf(x.w);
    uu.u[4] = f2bf(y.x); uu.u[5] = f2bf(y.y); uu.u[6] = f2bf(y.z); uu.u[7] = f2bf(y.w);
    afrag[kt] = uu.v;
  }

  f32x4 acc[24];
  #pragma unroll
  for (int t = 0; t < 24; ++t) acc[t] = (f32x4){0.f, 0.f, 0.f, 0.f};

  #pragma unroll
  for (int kt = 0; kt < 4; ++kt) {
    #pragma unroll
    for (int t = 0; t < 24; ++t) {
      bf16x8 b = *(const bf16x8*)(Wb + (size_t)(t * 16 + m) * EMBC + kt * 32 + q * 8);
      acc[t] = __builtin_amdgcn_mfma_f32_16x16x32_bf16(afrag[kt], b, acc[t], 0, 0, 0);
    }
  }

  // epilogue: +bias, bf16 to LDS (transpose), then coalesced uint4 store-out
  #pragma unroll
  for (int t = 0; t < 24; ++t) {
    int col = t * 16 + m;
    float bias = biasc[col];
    #pragma unroll
    for (int r = 0; r < 4; ++r)
      Ls[w * 16 + q * 4 + r][col] = (bhalf)f2bf(acc[t][r] + bias);
  }
  __syncthreads();
  for (int i = tid; i < 64 * 48; i += 256) {
    int r = i / 48, c = i % 48;          // c: 8-bf16 (16B) chunk
    int n2 = n0 + r;
    if (n2 < N) {
      uint4 v = *(const uint4*)&Ls[r][c * 8];
      int col = c * 8;
      bhalf* dst = (col < HCC) ? (xlb + (size_t)n2 * HCC + col)
                               : (xrb + (size_t)n2 * HCC + col - HCC);
      *(uint4*)dst = v;
    }
  }
}

// ---- pj[n,h] = pe[n,:].vh[h] + ch[h]  (fp32-exact value path) ----
// 16 lanes per node, 8 floats per lane.
__global__ __launch_bounds__(256) void pj_kernel(
    const float* __restrict__ pe, const float* __restrict__ vh,
    const float* __restrict__ ch, float* __restrict__ pj, int N)
{
  int tid = threadIdx.x;
  int n   = blockIdx.x * 16 + (tid >> 4);
  int l   = tid & 15;
  if (n >= N) return;   // uniform within each 16-lane group
  const float* p = pe + (size_t)n * EMBC + l * 8;
  float4 a = *(const float4*)p;
  float4 b = *(const float4*)(p + 4);
  float s[3];
  #pragma unroll
  for (int h = 0; h < 3; ++h) {
    const float* v = vh + h * EMBC + l * 8;
    float4 va = *(const float4*)v;
    float4 vb = *(const float4*)(v + 4);
    s[h] = a.x*va.x + a.y*va.y + a.z*va.z + a.w*va.w
         + b.x*vb.x + b.y*vb.y + b.z*vb.z + b.w*vb.w;
  }
  #pragma unroll
  for (int h = 0; h < 3; ++h) {
    s[h] += __shfl_xor(s[h], 1);
    s[h] += __shfl_xor(s[h], 2);
    s[h] += __shfl_xor(s[h], 4);
    s[h] += __shfl_xor(s[h], 8);
  }
  if (l < 3) pj[n * 3 + l] = (l == 0 ? s[0] : l == 1 ? s[1] : s[2]) + ch[l];
}

// ---- edge pass: 4 edges per wave, gathers issued up-front for MLP ----
#define EPW 4
__global__ __launch_bounds__(256) void edge_kernel(
    const int* __restrict__ ei, const float* __restrict__ ea,
    const bhalf* __restrict__ xlb, const bhalf* __restrict__ xrb,
    const float* __restrict__ pj, const float* __restrict__ We,
    const float* __restrict__ att,
    float* __restrict__ asum, float* __restrict__ numer, int E)
{
  int wave = (blockIdx.x * 256 + threadIdx.x) >> 6;
  int lane = threadIdx.x & 63;
  int e0 = wave * EPW;
  if (e0 >= E) return;
  int cnt = E - e0; if (cnt > EPW) cnt = EPW;

  int srcj[EPW], dstj[EPW]; float eavj[EPW];
  #pragma unroll
  for (int j = 0; j < EPW; ++j) {
    int e = e0 + (j < cnt ? j : 0);
    srcj[j] = ei[e]; dstj[j] = ei[E + e]; eavj[j] = ea[e];
  }

  const bool act = lane < 48;
  const int  lq  = lane >> 4;          // head for reducer lanes
  float4 wev = make_float4(0,0,0,0), atv = make_float4(0,0,0,0);
  uint2 ul[EPW], ur[EPW];
  float pjv[EPW];
  if (act) {
    wev = *(const float4*)(We + lane * 4);
    atv = *(const float4*)(att + lane * 4);
    #pragma unroll
    for (int j = 0; j < EPW; ++j) {
      ul[j] = *(const uint2*)(xlb + (size_t)srcj[j] * HCC + lane * 4);
      ur[j] = *(const uint2*)(xrb + (size_t)dstj[j] * HCC + lane * 4);
    }
    if ((lane & 15) == 0) {
      #pragma unroll
      for (int j = 0; j < EPW; ++j) pjv[j] = pj[srcj[j] * 3 + lq];
    }
  }

  #pragma unroll
  for (int j = 0; j < EPW; ++j) {
    float s = 0.f;
    if (act) {
      float m0 = __uint_as_float(ul[j].x << 16)         + __uint_as_float(ur[j].x << 16)         + eavj[j] * wev.x;
      float m1 = __uint_as_float(ul[j].x & 0xFFFF0000u) + __uint_as_float(ur[j].x & 0xFFFF0000u) + eavj[j] * wev.y;
      float m2 = __uint_as_float(ul[j].y << 16)         + __uint_as_float(ur[j].y << 16)         + eavj[j] * wev.z;
      float m3 = __uint_as_float(ul[j].y & 0xFFFF0000u) + __uint_as_float(ur[j].y & 0xFFFF0000u) + eavj[j] * wev.w;
      s = (m0 > 0.f ? m0 : 0.2f*m0) * atv.x
        + (m1 > 0.f ? m1 : 0.2f*m1) * atv.y
        + (m2 > 0.f ? m2 : 0.2f*m2) * atv.z
        + (m3 > 0.f ? m3 : 0.2f*m3) * atv.w;
    }
    s += __shfl_xor(s, 8);
    s += __shfl_xor(s, 4);
    s += __shfl_xor(s, 2);
    s += __shfl_xor(s, 1);
    if (act && (lane & 15) == 0 && j < cnt) {
      float ex = __expf(s);   // |a| small by construction: max-free softmax safe
      atomicAdd(asum  + dstj[j] * 3 + lq, ex);
      atomicAdd(numer + dstj[j] * 3 + lq, ex * pjv[j]);
    }
  }
}

// ---- scores[n] = (1/3) sum_h numer/asum ; block-reduce max ----
__global__ __launch_bounds__(256) void score_kernel(
    const float* __restrict__ numer, const float* __restrict__ asum,
    float* __restrict__ scores, unsigned* __restrict__ smax, int N)
{
  int n = blockIdx.x * 256 + threadIdx.x;
  int t = threadIdx.x;
  float s = -FLT_MAX;
  if (n < N) {
    float acc = 0.f;
    #pragma unroll
    for (int h = 0; h < 3; ++h) {
      float d = asum[n * 3 + h];
      if (d > 0.f) acc += numer[n * 3 + h] / d;   // empty segment -> 0
    }
    s = acc / 3.f;
    scores[n] = s;
  }
  __shared__ float red[256];
  red[t] = s;
  __syncthreads();
  for (int w = 128; w; w >>= 1) {
    if (t < w) red[t] = fmaxf(red[t], red[t + w]);
    __syncthreads();
  }
  if (t == 0) atomicMax(smax, fmap(red[0]));
}

__global__ __launch_bounds__(256) void expsum_kernel(
    const float* __restrict__ scores, const unsigned* __restrict__ smax,
    float* __restrict__ sumexp, float* __restrict__ out, int N)
{
  int n = blockIdx.x * 256 + threadIdx.x;
  int t = threadIdx.x;
  float m = funmap(*smax);
  float e = 0.f;
  if (n < N) {
    e = expf(scores[n] - m);
    out[n] = e;
  }
  __shared__ float red[256];
  red[t] = e;
  __syncthreads();
  for (int w = 128; w; w >>= 1) {
    if (t < w) red[t] += red[t + w];
    __syncthreads();
  }
  if (t == 0) atomicAdd(sumexp, red[0]);
}

__global__ __launch_bounds__(256) void norm_kernel(
    float* __restrict__ out, const float* __restrict__ sumexp, int N)
{
  int n = blockIdx.x * 256 + threadIdx.x;
  if (n < N) out[n] /= *sumexp;
}

extern "C" void kernel_launch(void* const* d_in, const int* in_sizes, int n_in,
                              void* d_out, int out_size, void* d_ws, size_t ws_size,
                              hipStream_t stream) {
  const int*   ei   = (const int*)  d_in[0];
  const float* ea   = (const float*)d_in[1];
  const float* pe   = (const float*)d_in[2];
  // d_in[3] sim_w: softmax over 1 element == 1.0 -> unused
  const float* Wl   = (const float*)d_in[4];
  const float* bl   = (const float*)d_in[5];
  const float* Wr   = (const float*)d_in[6];
  const float* br   = (const float*)d_in[7];
  const float* We   = (const float*)d_in[8];
  const float* att  = (const float*)d_in[9];
  // d_in[10] bias_gnn, d_in[12] bout: softmax-invariant constant shift, unused
  const float* Wout = (const float*)d_in[11];

  const int E = in_sizes[0] / 2;
  const int N = in_sizes[2] / EMBC;
  float* out = (float*)d_out;

  // workspace layout (16B-aligned sections)
  float* ws      = (float*)d_ws;
  float* asum    = ws;                               // 3N
  float* numer   = ws + (size_t)3 * N;               // 3N
  unsigned* smax = (unsigned*)(ws + (size_t)6 * N);  // 1 (mapped, 0 == -inf)
  float* sumexp  = ws + (size_t)6 * N + 1;           // 1
  float* pj      = ws + (size_t)6 * N + 16;          // 3N
  float* scores  = pj + (size_t)3 * N;               // N
  float* vh      = scores + N;                       // 384
  float* ch      = vh + 384;                         // 3 (+pad to 16)
  float* biasc   = ch + 16;                          // 384
  bhalf* Wb      = (bhalf*)(biasc + 384);            // 384*128 bf16
  bhalf* xlb     = Wb + (size_t)WCOLS * EMBC;        // N*192 bf16
  bhalf* xrb     = xlb + (size_t)N * HCC;            // N*192 bf16

  // zero the accumulators (ws is poisoned 0xAA before every call)
  hipMemsetAsync(ws, 0, ((size_t)6 * N + 2) * sizeof(float), stream);

  prep_kernel  <<<(WCOLS*EMBC + 771 + 255) / 256, 256, 0, stream>>>(Wl, Wr, bl, br, Wout, Wb, vh, biasc, ch);
  gemm_kernel  <<<(N + 63) / 64,    256, 0, stream>>>(pe, Wb, biasc, xlb, xrb, N);
  pj_kernel    <<<(N + 15) / 16,    256, 0, stream>>>(pe, vh, ch, pj, N);
  edge_kernel  <<<((E + EPW - 1) / EPW * 64 + 255) / 256, 256, 0, stream>>>(ei, ea, xlb, xrb, pj, We, att, asum, numer, E);
  score_kernel <<<(N + 255) / 256,  256, 0, stream>>>(numer, asum, scores, smax, N);
  expsum_kernel<<<(N + 255) / 256,  256, 0, stream>>>(scores, smax, sumexp, out, N);
  norm_kernel  <<<(N + 255) / 256,  256, 0, stream>>>(out, sumexp, N);
}

// Round 5
// 266.237 us; speedup vs baseline: 1.7580x; 1.1037x over previous
//
#include <hip/hip_runtime.h>
#include <cfloat>
#include <cmath>

#define NHEADS 3
#define HIDC   64
#define HCC    192   // NHEADS*HIDC
#define EMBC   128
#define WCOLS  384   // 2*HCC (Wl rows ++ Wr rows)

typedef unsigned short bhalf;
typedef __attribute__((ext_vector_type(8))) short bf16x8;
typedef __attribute__((ext_vector_type(4))) float f32x4;
typedef __attribute__((ext_vector_type(2))) float f32x2;

__device__ __forceinline__ unsigned f2bf(float f) {   // RNE fp32 -> bf16 bits
  unsigned u = __float_as_uint(f);
  return (u + 0x7FFFu + ((u >> 16) & 1u)) >> 16;
}

// ---- prep: Wb bf16[384][128]; vh[3][128]; ch[3]; b16=16*bias[384];
//            We16=16*We[192]; att16=att/16[192].
// Scale trick: store fp8 of 16*x (leakyrelu is positively homogeneous;
// 1/16 folded into att16) -> fp8 values land in well-normalized range.
__global__ __launch_bounds__(256) void prep_kernel(
    const float* __restrict__ Wl, const float* __restrict__ Wr,
    const float* __restrict__ bl, const float* __restrict__ br,
    const float* __restrict__ Wout, const float* __restrict__ We,
    const float* __restrict__ att,
    bhalf* __restrict__ Wb, float* __restrict__ vh, float* __restrict__ b16,
    float* __restrict__ We16, float* __restrict__ att16, float* __restrict__ ch)
{
  int gt = blockIdx.x * 256 + threadIdx.x;
  if (gt < WCOLS * EMBC) {                              // Wb (bf16 RNE)
    int c = gt >> 7, k = gt & 127;
    float v = (c < HCC) ? Wl[c * EMBC + k] : Wr[(c - HCC) * EMBC + k];
    Wb[gt] = (bhalf)f2bf(v);
  } else if (gt < WCOLS * EMBC + 384) {                 // vh (3*128, fp32 value path)
    int i = gt - WCOLS * EMBC;
    int h = i >> 7, k = i & 127;
    float s = 0.f;
    for (int c = 0; c < HIDC; ++c)
      s += Wout[c] * Wl[(h * HIDC + c) * EMBC + k];
    vh[i] = s;
  } else if (gt < WCOLS * EMBC + 768) {                 // b16 = 16*(bl++br)
    int c = gt - WCOLS * EMBC - 384;
    b16[c] = 16.f * ((c < HCC) ? bl[c] : br[c - HCC]);
  } else if (gt < WCOLS * EMBC + 960) {                 // We16
    int c = gt - WCOLS * EMBC - 768;
    We16[c] = 16.f * We[c];
  } else if (gt < WCOLS * EMBC + 1152) {                // att16
    int c = gt - WCOLS * EMBC - 960;
    att16[c] = att[c] * (1.f / 16.f);
  } else if (gt < WCOLS * EMBC + 1155) {                // ch
    int h = gt - WCOLS * EMBC - 1152;
    float s = 0.f;
    for (int c = 0; c < HIDC; ++c) s += bl[h * HIDC + c] * Wout[c];
    ch[h] = s;
  }
}

// ---- MFMA GEMM: [xl|xr](fp8 of 16*val) = pe @ [Wl;Wr]^T + bias; pj fused ----
// OPERAND SWAP: mfma(Wfrag, pefrag) -> D col(lane&15)=node, row(q*4+reg)=wcol.
// Each lane's 4 acc values = 4 CONSECUTIVE wcols of one node row -> one fp8
// dword -> direct global store (no LDS transpose at all).
__global__ __launch_bounds__(256) void gemm_kernel(
    const float* __restrict__ pe, const bhalf* __restrict__ Wb,
    const float* __restrict__ b16, const float* __restrict__ vh,
    const float* __restrict__ ch,
    unsigned char* __restrict__ xl8, unsigned char* __restrict__ xr8,
    float* __restrict__ pj, int N)
{
  const int tid  = threadIdx.x;
  const int w    = tid >> 6;
  const int lane = tid & 63;
  const int m    = lane & 15;
  const int q    = lane >> 4;
  const int n0   = blockIdx.x * 64;
  const int node = n0 + w * 16 + m;
  const size_t prow = (size_t)(node < N ? node : N - 1) * EMBC;

  // pe fragments (B-operand): 8 k-elems/lane per k-tile; pj partials in fp32
  bf16x8 pfrag[4];
  float pjp[3] = {0.f, 0.f, 0.f};
  #pragma unroll
  for (int kt = 0; kt < 4; ++kt) {
    const float* p = pe + prow + kt * 32 + q * 8;
    float4 x = *(const float4*)p;
    float4 y = *(const float4*)(p + 4);
    #pragma unroll
    for (int h = 0; h < 3; ++h) {
      const float* v = vh + h * EMBC + kt * 32 + q * 8;
      float4 va = *(const float4*)v;
      float4 vb = *(const float4*)(v + 4);
      pjp[h] += x.x*va.x + x.y*va.y + x.z*va.z + x.w*va.w
              + y.x*vb.x + y.y*vb.y + y.z*vb.z + y.w*vb.w;
    }
    union { bf16x8 v; unsigned u[4]; } uu;   // trunc-pack pe -> bf16 (err << fp8 store err)
    uu.u[0] = (__float_as_uint(x.x) >> 16) | (__float_as_uint(x.y) & 0xFFFF0000u);
    uu.u[1] = (__float_as_uint(x.z) >> 16) | (__float_as_uint(x.w) & 0xFFFF0000u);
    uu.u[2] = (__float_as_uint(y.x) >> 16) | (__float_as_uint(y.y) & 0xFFFF0000u);
    uu.u[3] = (__float_as_uint(y.z) >> 16) | (__float_as_uint(y.w) & 0xFFFF0000u);
    pfrag[kt] = uu.v;
  }

  f32x4 acc[24];
  #pragma unroll
  for (int t = 0; t < 24; ++t) acc[t] = (f32x4){0.f, 0.f, 0.f, 0.f};

  #pragma unroll
  for (int kt = 0; kt < 4; ++kt) {
    #pragma unroll
    for (int t = 0; t < 24; ++t) {
      bf16x8 wf = *(const bf16x8*)(Wb + (size_t)(t * 16 + m) * EMBC + kt * 32 + q * 8);
      acc[t] = __builtin_amdgcn_mfma_f32_16x16x32_bf16(wf, pfrag[kt], acc[t], 0, 0, 0);
    }
  }

  // pj: reduce the 4 q-copies of node m (lanes m, m+16, m+32, m+48)
  #pragma unroll
  for (int h = 0; h < 3; ++h) {
    pjp[h] += __shfl_xor(pjp[h], 16);
    pjp[h] += __shfl_xor(pjp[h], 32);
  }
  if (q == 0 && node < N) {
    pj[node * 3 + 0] = pjp[0] + ch[0];
    pj[node * 3 + 1] = pjp[1] + ch[1];
    pj[node * 3 + 2] = pjp[2] + ch[2];
  }

  // epilogue: r = 16*acc + b16, fp8-pack 4 consecutive wcols, direct dword store
  if (node < N) {
    #pragma unroll
    for (int t = 0; t < 24; ++t) {
      int col = t * 16 + q * 4;
      float4 b = *(const float4*)(b16 + col);
      float r0 = fmaf(acc[t][0], 16.f, b.x);
      float r1 = fmaf(acc[t][1], 16.f, b.y);
      float r2 = fmaf(acc[t][2], 16.f, b.z);
      float r3 = fmaf(acc[t][3], 16.f, b.w);
      int p = 0;
      p = __builtin_amdgcn_cvt_pk_fp8_f32(r0, r1, p, false);
      p = __builtin_amdgcn_cvt_pk_fp8_f32(r2, r3, p, true);
      unsigned char* dst = (col < HCC) ? xl8 + (size_t)node * HCC + col
                                       : xr8 + (size_t)node * HCC + col - HCC;
      *(unsigned*)dst = (unsigned)p;
    }
  }
}

// ---- edge pass: 8 edges/wave, fp8 rows (4B/lane), gathers issued up-front ----
#define EPW 8
__global__ __launch_bounds__(256) void edge_kernel(
    const int* __restrict__ ei, const float* __restrict__ ea,
    const unsigned char* __restrict__ xl8, const unsigned char* __restrict__ xr8,
    const float* __restrict__ pj, const float* __restrict__ We16,
    const float* __restrict__ att16,
    float* __restrict__ asum, float* __restrict__ numer, int E)
{
  int wave = (blockIdx.x * 256 + threadIdx.x) >> 6;
  int lane = threadIdx.x & 63;
  int e0 = wave * EPW;
  if (e0 >= E) return;
  int cnt = E - e0; if (cnt > EPW) cnt = EPW;

  int srcj[EPW], dstj[EPW]; float eavj[EPW];
  #pragma unroll
  for (int j = 0; j < EPW; ++j) {
    int e = e0 + (j < cnt ? j : 0);
    srcj[j] = ei[e]; dstj[j] = ei[E + e]; eavj[j] = ea[e];
  }

  const bool act = lane < 48;
  const int  lq  = lane >> 4;          // head for reducer lanes
  float4 wev = make_float4(0,0,0,0), atv = make_float4(0,0,0,0);
  unsigned ul[EPW], ur[EPW];
  float pjv[EPW];
  if (act) {
    wev = *(const float4*)(We16 + lane * 4);
    atv = *(const float4*)(att16 + lane * 4);
    #pragma unroll
    for (int j = 0; j < EPW; ++j) {     // 32-bit offsets -> saddr+voffset form
      unsigned offl = (unsigned)srcj[j] * 192u + (unsigned)lane * 4u;
      unsigned offr = (unsigned)dstj[j] * 192u + (unsigned)lane * 4u;
      ul[j] = *(const unsigned*)(xl8 + offl);
      ur[j] = *(const unsigned*)(xr8 + offr);
    }
    if ((lane & 15) == 0) {
      #pragma unroll
      for (int j = 0; j < EPW; ++j) pjv[j] = pj[srcj[j] * 3 + lq];
    }
  }

  #pragma unroll
  for (int j = 0; j < EPW; ++j) {
    float s = 0.f;
    if (act) {
      f32x2 llo = __builtin_amdgcn_cvt_pk_f32_fp8(ul[j], false);
      f32x2 lhi = __builtin_amdgcn_cvt_pk_f32_fp8(ul[j], true);
      f32x2 rlo = __builtin_amdgcn_cvt_pk_f32_fp8(ur[j], false);
      f32x2 rhi = __builtin_amdgcn_cvt_pk_f32_fp8(ur[j], true);
      float m0 = llo.x + rlo.x + eavj[j] * wev.x;    // all values are 16x scaled
      float m1 = llo.y + rlo.y + eavj[j] * wev.y;
      float m2 = lhi.x + rhi.x + eavj[j] * wev.z;
      float m3 = lhi.y + rhi.y + eavj[j] * wev.w;
      s = fmaxf(m0, 0.2f * m0) * atv.x               // lrelu(16m)=16*lrelu(m); /16 in att16
        + fmaxf(m1, 0.2f * m1) * atv.y
        + fmaxf(m2, 0.2f * m2) * atv.z
        + fmaxf(m3, 0.2f * m3) * atv.w;
    }
    s += __shfl_xor(s, 8);
    s += __shfl_xor(s, 4);
    s += __shfl_xor(s, 2);
    s += __shfl_xor(s, 1);
    if (act && (lane & 15) == 0 && j < cnt) {
      float ex = __expf(s);   // |a| small by construction: max-free softmax safe
      atomicAdd(asum  + dstj[j] * 3 + lq, ex);
      atomicAdd(numer + dstj[j] * 3 + lq, ex * pjv[j]);
    }
  }
}

// ---- out[n] = exp(score); global sum via atomics (|score|<1: no max shift) ----
__global__ __launch_bounds__(256) void scoreexp_kernel(
    const float* __restrict__ numer, const float* __restrict__ asum,
    float* __restrict__ sumexp, float* __restrict__ out, int N)
{
  int n = blockIdx.x * 256 + threadIdx.x;
  int t = threadIdx.x;
  float e = 0.f;
  if (n < N) {
    float acc = 0.f;
    #pragma unroll
    for (int h = 0; h < 3; ++h) {
      float d = asum[n * 3 + h];
      if (d > 0.f) acc += numer[n * 3 + h] / d;   // empty segment -> 0
    }
    e = expf(acc * (1.f / 3.f));
    out[n] = e;
  }
  __shared__ float red[256];
  red[t] = e;
  __syncthreads();
  for (int w = 128; w; w >>= 1) {
    if (t < w) red[t] += red[t + w];
    __syncthreads();
  }
  if (t == 0) atomicAdd(sumexp, red[0]);
}

__global__ __launch_bounds__(256) void norm_kernel(
    float* __restrict__ out, const float* __restrict__ sumexp, int N)
{
  int n = blockIdx.x * 256 + threadIdx.x;
  if (n < N) out[n] /= *sumexp;
}

extern "C" void kernel_launch(void* const* d_in, const int* in_sizes, int n_in,
                              void* d_out, int out_size, void* d_ws, size_t ws_size,
                              hipStream_t stream) {
  const int*   ei   = (const int*)  d_in[0];
  const float* ea   = (const float*)d_in[1];
  const float* pe   = (const float*)d_in[2];
  // d_in[3] sim_w: softmax over 1 element == 1.0 -> unused
  const float* Wl   = (const float*)d_in[4];
  const float* bl   = (const float*)d_in[5];
  const float* Wr   = (const float*)d_in[6];
  const float* br   = (const float*)d_in[7];
  const float* We   = (const float*)d_in[8];
  const float* att  = (const float*)d_in[9];
  // d_in[10] bias_gnn, d_in[12] bout: softmax-invariant constant shift, unused
  const float* Wout = (const float*)d_in[11];

  const int E = in_sizes[0] / 2;
  const int N = in_sizes[2] / EMBC;
  float* out = (float*)d_out;

  // workspace layout (16B-aligned sections)
  float* ws      = (float*)d_ws;
  float* asum    = ws;                               // 3N
  float* numer   = ws + (size_t)3 * N;               // 3N
  float* sumexp  = ws + (size_t)6 * N;               // 1 (pad 16)
  float* pj      = ws + (size_t)6 * N + 16;          // 3N
  float* vh      = pj + (size_t)3 * N;               // 384
  float* b16     = vh + 384;                         // 384
  float* We16    = b16 + 384;                        // 192
  float* att16   = We16 + 192;                       // 192
  float* ch      = att16 + 192;                      // 3 (+pad 16)
  bhalf* Wb      = (bhalf*)(ch + 16);                // 384*128 bf16
  unsigned char* xl8 = (unsigned char*)(Wb + (size_t)WCOLS * EMBC);  // N*192 fp8
  unsigned char* xr8 = xl8 + (size_t)N * HCC;                        // N*192 fp8

  // zero the accumulators (ws is poisoned 0xAA before every call)
  hipMemsetAsync(ws, 0, ((size_t)6 * N + 1) * sizeof(float), stream);

  prep_kernel  <<<(WCOLS*EMBC + 1155 + 255) / 256, 256, 0, stream>>>(
      Wl, Wr, bl, br, Wout, We, att, Wb, vh, b16, We16, att16, ch);
  gemm_kernel  <<<(N + 63) / 64, 256, 0, stream>>>(pe, Wb, b16, vh, ch, xl8, xr8, pj, N);
  edge_kernel  <<<((E + EPW - 1) / EPW * 64 + 255) / 256, 256, 0, stream>>>(
      ei, ea, xl8, xr8, pj, We16, att16, asum, numer, E);
  scoreexp_kernel<<<(N + 255) / 256, 256, 0, stream>>>(numer, asum, sumexp, out, N);
  norm_kernel  <<<(N + 255) / 256, 256, 0, stream>>>(out, sumexp, N);
}

// Round 6
// 232.892 us; speedup vs baseline: 2.0097x; 1.1432x over previous
//
#include <hip/hip_runtime.h>
#include <cfloat>
#include <cmath>

#define NHEADS 3
#define HIDC   64
#define HCC    192   // NHEADS*HIDC
#define EMBC   128
#define WCOLS  384   // 2*HCC (Wl rows ++ Wr rows)

typedef unsigned short bhalf;
typedef __attribute__((ext_vector_type(8))) short bf16x8;
typedef __attribute__((ext_vector_type(4))) float f32x4;
typedef __attribute__((ext_vector_type(2))) float f32x2;

__device__ __forceinline__ unsigned f2bf(float f) {   // RNE fp32 -> bf16 bits
  unsigned u = __float_as_uint(f);
  return (u + 0x7FFFu + ((u >> 16) & 1u)) >> 16;
}

// ---- prep: Wb bf16[384][128]; vh[3][128]; ch[3]; b16=16*bias[384];
//            We16=16*We[192]; att16=att/16[192].
// Scale trick: store fp8 of 16*x (leakyrelu positively homogeneous; 1/16
// folded into att16) -> fp8 values land in well-normalized range.
__global__ __launch_bounds__(256) void prep_kernel(
    const float* __restrict__ Wl, const float* __restrict__ Wr,
    const float* __restrict__ bl, const float* __restrict__ br,
    const float* __restrict__ Wout, const float* __restrict__ We,
    const float* __restrict__ att,
    bhalf* __restrict__ Wb, float* __restrict__ vh, float* __restrict__ b16,
    float* __restrict__ We16, float* __restrict__ att16, float* __restrict__ ch)
{
  int gt = blockIdx.x * 256 + threadIdx.x;
  if (gt < WCOLS * EMBC) {                              // Wb (bf16 RNE)
    int c = gt >> 7, k = gt & 127;
    float v = (c < HCC) ? Wl[c * EMBC + k] : Wr[(c - HCC) * EMBC + k];
    Wb[gt] = (bhalf)f2bf(v);
  } else if (gt < WCOLS * EMBC + 384) {                 // vh (3*128, fp32 value path)
    int i = gt - WCOLS * EMBC;
    int h = i >> 7, k = i & 127;
    float s = 0.f;
    for (int c = 0; c < HIDC; ++c)
      s += Wout[c] * Wl[(h * HIDC + c) * EMBC + k];
    vh[i] = s;
  } else if (gt < WCOLS * EMBC + 768) {                 // b16 = 16*(bl++br)
    int c = gt - WCOLS * EMBC - 384;
    b16[c] = 16.f * ((c < HCC) ? bl[c] : br[c - HCC]);
  } else if (gt < WCOLS * EMBC + 960) {                 // We16
    int c = gt - WCOLS * EMBC - 768;
    We16[c] = 16.f * We[c];
  } else if (gt < WCOLS * EMBC + 1152) {                // att16
    int c = gt - WCOLS * EMBC - 960;
    att16[c] = att[c] * (1.f / 16.f);
  } else if (gt < WCOLS * EMBC + 1155) {                // ch
    int h = gt - WCOLS * EMBC - 1152;
    float s = 0.f;
    for (int c = 0; c < HIDC; ++c) s += bl[h * HIDC + c] * Wout[c];
    ch[h] = s;
  }
}

// ---- MFMA GEMM with LDS-staged W (k-split halves), pj fused ----
// Operand swap: mfma(Wfrag, pefrag) -> D col(lane&15)=node, row(q*4+reg)=wcol;
// each lane's 4 accs = 4 consecutive wcols -> one fp8 dword, direct store.
// Ws row stride 72 elems (144 B): bank group = 4*(m+q)%32 -> 2-way alias (free).
__global__ __launch_bounds__(256) void gemm_kernel(
    const float* __restrict__ pe, const bhalf* __restrict__ Wb,
    const float* __restrict__ b16, const float* __restrict__ vh,
    const float* __restrict__ ch,
    unsigned char* __restrict__ xl8, unsigned char* __restrict__ xr8,
    float* __restrict__ pj, int N)
{
  __shared__ bhalf Ws[WCOLS * 72];   // 55296 B: one 64-k half of W, padded
  const int tid  = threadIdx.x;
  const int w    = tid >> 6;
  const int lane = tid & 63;
  const int m    = lane & 15;
  const int q    = lane >> 4;
  const int n0   = blockIdx.x * 64;
  const int node = n0 + w * 16 + m;
  const size_t prow = (size_t)(node < N ? node : N - 1) * EMBC;

  // pe fragments (B-operand): 8 k-elems/lane per 32-k tile; pj partials fp32
  bf16x8 pfrag[4];
  float pjp[3] = {0.f, 0.f, 0.f};
  #pragma unroll
  for (int kt = 0; kt < 4; ++kt) {
    const float* p = pe + prow + kt * 32 + q * 8;
    float4 x = *(const float4*)p;
    float4 y = *(const float4*)(p + 4);
    #pragma unroll
    for (int h = 0; h < 3; ++h) {
      const float* v = vh + h * EMBC + kt * 32 + q * 8;
      float4 va = *(const float4*)v;
      float4 vb = *(const float4*)(v + 4);
      pjp[h] += x.x*va.x + x.y*va.y + x.z*va.z + x.w*va.w
              + y.x*vb.x + y.y*vb.y + y.z*vb.z + y.w*vb.w;
    }
    union { bf16x8 v; unsigned u[4]; } uu;   // trunc-pack pe -> bf16
    uu.u[0] = (__float_as_uint(x.x) >> 16) | (__float_as_uint(x.y) & 0xFFFF0000u);
    uu.u[1] = (__float_as_uint(x.z) >> 16) | (__float_as_uint(x.w) & 0xFFFF0000u);
    uu.u[2] = (__float_as_uint(y.x) >> 16) | (__float_as_uint(y.y) & 0xFFFF0000u);
    uu.u[3] = (__float_as_uint(y.z) >> 16) | (__float_as_uint(y.w) & 0xFFFF0000u);
    pfrag[kt] = uu.v;
  }

  f32x4 acc[24];
  #pragma unroll
  for (int t = 0; t < 24; ++t) acc[t] = (f32x4){0.f, 0.f, 0.f, 0.f};

  for (int kh = 0; kh < 2; ++kh) {
    __syncthreads();                         // protect Ws reuse
    for (int f = tid; f < WCOLS * 8; f += 256) {   // stage 64-k half, coalesced
      int cc = f >> 3, s = f & 7;                  // s: 16B slot (8 bf16)
      uint4 v = *(const uint4*)(Wb + (size_t)cc * EMBC + kh * 64 + s * 8);
      *(uint4*)(Ws + cc * 72 + s * 8) = v;
    }
    __syncthreads();
    #pragma unroll
    for (int kt2 = 0; kt2 < 2; ++kt2) {
      #pragma unroll
      for (int t = 0; t < 24; ++t) {
        bf16x8 wf = *(const bf16x8*)(Ws + (t * 16 + m) * 72 + kt2 * 32 + q * 8);
        acc[t] = __builtin_amdgcn_mfma_f32_16x16x32_bf16(wf, pfrag[kh * 2 + kt2], acc[t], 0, 0, 0);
      }
    }
  }

  // pj: reduce the 4 q-copies of node m (lanes m, m+16, m+32, m+48)
  #pragma unroll
  for (int h = 0; h < 3; ++h) {
    pjp[h] += __shfl_xor(pjp[h], 16);
    pjp[h] += __shfl_xor(pjp[h], 32);
  }
  if (q == 0 && node < N) {
    pj[node * 3 + 0] = pjp[0] + ch[0];
    pj[node * 3 + 1] = pjp[1] + ch[1];
    pj[node * 3 + 2] = pjp[2] + ch[2];
  }

  // epilogue: r = 16*acc + b16, fp8-pack 4 consecutive wcols, direct dword store
  if (node < N) {
    #pragma unroll
    for (int t = 0; t < 24; ++t) {
      int col = t * 16 + q * 4;
      float4 b = *(const float4*)(b16 + col);
      float r0 = fmaf(acc[t][0], 16.f, b.x);
      float r1 = fmaf(acc[t][1], 16.f, b.y);
      float r2 = fmaf(acc[t][2], 16.f, b.z);
      float r3 = fmaf(acc[t][3], 16.f, b.w);
      int p = 0;
      p = __builtin_amdgcn_cvt_pk_fp8_f32(r0, r1, p, false);
      p = __builtin_amdgcn_cvt_pk_fp8_f32(r2, r3, p, true);
      unsigned char* dst = (col < HCC) ? xl8 + (size_t)node * HCC + col
                                       : xr8 + (size_t)node * HCC + col - HCC;
      *(unsigned*)dst = (unsigned)p;
    }
  }
}

// ---- edge pass: 12 lanes/edge, uint4 (16 fp8) per lane, 5 edges/group ----
#define GPW 2   // groups per wave -> 10 edges/wave, 4 row-gathers in flight
#define EPG 5
__global__ __launch_bounds__(256) void edge_kernel(
    const int* __restrict__ ei, const float* __restrict__ ea,
    const unsigned char* __restrict__ xl8, const unsigned char* __restrict__ xr8,
    const float* __restrict__ pj, const float* __restrict__ We16,
    const float* __restrict__ att16,
    float* __restrict__ asum, float* __restrict__ numer, int E)
{
  int wave = (blockIdx.x * 256 + threadIdx.x) >> 6;
  int lane = threadIdx.x & 63;
  int j = lane / 12;          // edge within group (5 = idle tail lanes)
  int c = lane % 12;          // 16-byte chunk within row; head h = c>>2
  bool act = lane < 60;
  int e00 = wave * (GPW * EPG);
  if (e00 >= E) return;

  // hoisted per-lane constant slices (L1-hot)
  int cc = act ? c : 0;
  float4 we[4], at[4];
  #pragma unroll
  for (int i = 0; i < 4; ++i) {
    we[i] = *(const float4*)(We16 + cc * 16 + i * 4);
    at[i] = *(const float4*)(att16 + cc * 16 + i * 4);
  }

  #pragma unroll
  for (int g = 0; g < GPW; ++g) {
    int e = e00 + g * EPG + j;
    bool ve = act && (e < E);
    int ec = (e < E) ? e : (E - 1);
    int src = ei[ec];
    int dst = ei[E + ec];
    float eav = ea[ec];
    uint4 ul = make_uint4(0, 0, 0, 0), ur = make_uint4(0, 0, 0, 0);
    if (act) {
      ul = *(const uint4*)(xl8 + (size_t)src * HCC + cc * 16);
      ur = *(const uint4*)(xr8 + (size_t)dst * HCC + cc * 16);
    }
    const unsigned* ulp = &ul.x;
    const unsigned* urp = &ur.x;
    float s = 0.f;
    #pragma unroll
    for (int i = 0; i < 4; ++i) {
      f32x2 l0 = __builtin_amdgcn_cvt_pk_f32_fp8(ulp[i], false);
      f32x2 l1 = __builtin_amdgcn_cvt_pk_f32_fp8(ulp[i], true);
      f32x2 r0 = __builtin_amdgcn_cvt_pk_f32_fp8(urp[i], false);
      f32x2 r1 = __builtin_amdgcn_cvt_pk_f32_fp8(urp[i], true);
      float m0 = l0.x + r0.x + eav * we[i].x;   // all values 16x-scaled
      float m1 = l0.y + r0.y + eav * we[i].y;
      float m2 = l1.x + r1.x + eav * we[i].z;
      float m3 = l1.y + r1.y + eav * we[i].w;
      s += fmaxf(m0, 0.2f * m0) * at[i].x       // lrelu(16m)=16*lrelu(m); /16 in att16
         + fmaxf(m1, 0.2f * m1) * at[i].y
         + fmaxf(m2, 0.2f * m2) * at[i].z
         + fmaxf(m3, 0.2f * m3) * at[i].w;
    }
    // head sum: quad (4 lanes) per head, quads are 4-aligned (j*12 ≡ 0 mod 4)
    s += __shfl_xor(s, 1);
    s += __shfl_xor(s, 2);
    if (ve && (c & 3) == 0) {
      int h = c >> 2;
      float ex = __expf(s);   // |a| small by construction: max-free softmax safe
      atomicAdd(asum  + dst * 3 + h, ex);
      atomicAdd(numer + dst * 3 + h, ex * pj[src * 3 + h]);
    }
  }
}

// ---- out[n] = exp(score); global sum via atomics (|score|<1: no max shift) ----
__global__ __launch_bounds__(256) void scoreexp_kernel(
    const float* __restrict__ numer, const float* __restrict__ asum,
    float* __restrict__ sumexp, float* __restrict__ out, int N)
{
  int n = blockIdx.x * 256 + threadIdx.x;
  int t = threadIdx.x;
  float e = 0.f;
  if (n < N) {
    float acc = 0.f;
    #pragma unroll
    for (int h = 0; h < 3; ++h) {
      float d = asum[n * 3 + h];
      if (d > 0.f) acc += numer[n * 3 + h] / d;   // empty segment -> 0
    }
    e = expf(acc * (1.f / 3.f));
    out[n] = e;
  }
  __shared__ float red[256];
  red[t] = e;
  __syncthreads();
  for (int w = 128; w; w >>= 1) {
    if (t < w) red[t] += red[t + w];
    __syncthreads();
  }
  if (t == 0) atomicAdd(sumexp, red[0]);
}

__global__ __launch_bounds__(256) void norm_kernel(
    float* __restrict__ out, const float* __restrict__ sumexp, int N)
{
  int n = blockIdx.x * 256 + threadIdx.x;
  if (n < N) out[n] /= *sumexp;
}

extern "C" void kernel_launch(void* const* d_in, const int* in_sizes, int n_in,
                              void* d_out, int out_size, void* d_ws, size_t ws_size,
                              hipStream_t stream) {
  const int*   ei   = (const int*)  d_in[0];
  const float* ea   = (const float*)d_in[1];
  const float* pe   = (const float*)d_in[2];
  // d_in[3] sim_w: softmax over 1 element == 1.0 -> unused
  const float* Wl   = (const float*)d_in[4];
  const float* bl   = (const float*)d_in[5];
  const float* Wr   = (const float*)d_in[6];
  const float* br   = (const float*)d_in[7];
  const float* We   = (const float*)d_in[8];
  const float* att  = (const float*)d_in[9];
  // d_in[10] bias_gnn, d_in[12] bout: softmax-invariant constant shift, unused
  const float* Wout = (const float*)d_in[11];

  const int E = in_sizes[0] / 2;
  const int N = in_sizes[2] / EMBC;
  float* out = (float*)d_out;

  // workspace layout (16B-aligned sections)
  float* ws      = (float*)d_ws;
  float* asum    = ws;                               // 3N
  float* numer   = ws + (size_t)3 * N;               // 3N
  float* sumexp  = ws + (size_t)6 * N;               // 1 (pad 16)
  float* pj      = ws + (size_t)6 * N + 16;          // 3N
  float* vh      = pj + (size_t)3 * N;               // 384
  float* b16     = vh + 384;                         // 384
  float* We16    = b16 + 384;                        // 192
  float* att16   = We16 + 192;                       // 192
  float* ch      = att16 + 192;                      // 3 (+pad 16)
  bhalf* Wb      = (bhalf*)(ch + 16);                // 384*128 bf16
  unsigned char* xl8 = (unsigned char*)(Wb + (size_t)WCOLS * EMBC);  // N*192 fp8
  unsigned char* xr8 = xl8 + (size_t)N * HCC;                        // N*192 fp8

  // zero the accumulators (ws is poisoned 0xAA before every call)
  hipMemsetAsync(ws, 0, ((size_t)6 * N + 1) * sizeof(float), stream);

  prep_kernel  <<<(WCOLS*EMBC + 1155 + 255) / 256, 256, 0, stream>>>(
      Wl, Wr, bl, br, Wout, We, att, Wb, vh, b16, We16, att16, ch);
  gemm_kernel  <<<(N + 63) / 64, 256, 0, stream>>>(pe, Wb, b16, vh, ch, xl8, xr8, pj, N);
  {
    int waves = (E + GPW * EPG - 1) / (GPW * EPG);
    edge_kernel<<<(waves * 64 + 255) / 256, 256, 0, stream>>>(
        ei, ea, xl8, xr8, pj, We16, att16, asum, numer, E);
  }
  scoreexp_kernel<<<(N + 255) / 256, 256, 0, stream>>>(numer, asum, sumexp, out, N);
  norm_kernel  <<<(N + 255) / 256, 256, 0, stream>>>(out, sumexp, N);
}